// Round 9
// baseline (778.108 us; speedup 1.0000x reference)
//
#include <hip/hip_runtime.h>
#include <stdint.h>

// Problem constants (match reference)
#define NN   100000   // nodes
#define FIN  500      // input features
#define HID  128      // hidden
#define KP1  512      // FIN padded to mult of 32 for MFMA K-loop
#define K2   256      // 2*HID (GEMM2 K)
#define CO   40       // classes
#define NPQ  80       // folded tail GEMM N (P|Q)
#define NPQP 128      // WpqT padded rows (uniform staging)
#define NBUCK 391     // ceil(NN/256) coarse buckets (target>>8)
#define CAPB_S 9216   // structural bucket capacity (mean 8184, +11 sigma)
#define CAPB_K 1536   // knn bucket capacity (mean 1279, +7 sigma)

typedef __attribute__((ext_vector_type(8))) short short8;
typedef __attribute__((ext_vector_type(4))) float float4v;
typedef __attribute__((address_space(3))) unsigned int as3_u32;
typedef __attribute__((address_space(1))) unsigned int as1_u32;

__device__ __forceinline__ unsigned short f2bf(float f) {
  unsigned u = __float_as_uint(f);
  u = u + 0x7fffu + ((u >> 16) & 1u);   // RNE
  return (unsigned short)(u >> 16);
}
__device__ __forceinline__ float bf2f(unsigned short s) {
  return __uint_as_float(((unsigned)s) << 16);
}
__device__ __forceinline__ void gl_lds16(const void* g, void* l) {
  __builtin_amdgcn_global_load_lds((const as1_u32*)g, (as3_u32*)l, 16, 0, 0);
}

// ---------------- fused phase 1: bin edges (+global deg histogram)  ||  weight prep ----------------
// blocks [0,nbBin): bin; [nbBin,nbBin+256): w1t; [nbBin+256,nbBin+256+80): wpq.
// bin now also accumulates per-node degree (deg[tgt]) -> csr pass 1 and k_fuse both die.
__global__ __launch_bounds__(256) void k_binw(
    const int* __restrict__ ei, int nS, int nb1S, int* __restrict__ gcur_s, int* __restrict__ gbin_s,
    const int* __restrict__ eik, int nK, int nbBin, int* __restrict__ gcur_k, int* __restrict__ gbin_k,
    int* __restrict__ deg_s, int* __restrict__ deg_k,
    const float* __restrict__ W1, unsigned short* __restrict__ W1T,
    const float* __restrict__ W2, const float* __restrict__ Wl,
    const float* __restrict__ b2, const float* __restrict__ bl,
    unsigned short* __restrict__ WpqT, float* __restrict__ cb) {
  __shared__ int cnt[NBUCK];
  __shared__ int base[NBUCK];
  const int t = threadIdx.x;

  if (blockIdx.x >= nbBin) {
    const int wb = blockIdx.x - nbBin;
    if (wb < 256) {                          // ---- w1t path ----
      const int idx = wb * 256 + t;          // 128*512
      const int n = idx >> 9, k = idx & 511;
      const float v = (k < FIN) ? W1[k * HID + n] : 0.f;
      W1T[idx] = f2bf(v);
    } else {                                 // ---- wpq path ----
      const int lb = wb - 256;               // 0..79
      const int idx = lb * 256 + t;
      const int n = idx >> 8, k = idx & 255;
      const int o = (n < CO) ? n : n - CO;
      const int joff = (n < CO) ? 0 : CO;
      float s = 0.f;
#pragma unroll 8
      for (int j = 0; j < CO; ++j) s += W2[k * CO + j] * Wl[o * NPQ + joff + j];
      WpqT[n * K2 + k] = f2bf(s);
      if (lb == 0 && t < CO) {
        const int oo = t;
        float c = bl[oo];
        for (int j = 0; j < CO; ++j) c += b2[j] * (Wl[oo * NPQ + j] + Wl[oo * NPQ + CO + j]);
        cb[oo] = c;
      }
    }
    return;
  }

  // ---- bin path ----
  const int b = blockIdx.x;
  const bool knn = (b >= nb1S);
  const int* src = knn ? eik      : ei;
  const int* tgt = knn ? eik + nK : ei + nS;
  const int n    = knn ? nK : nS;
  int* gcur      = knn ? gcur_k : gcur_s;
  int* gbin      = knn ? gbin_k : gbin_s;
  int* deg       = knn ? deg_k  : deg_s;
  const int capb = knn ? CAPB_K : CAPB_S;
  const int ebase = (knn ? b - nb1S : b) * 4096;

  for (int i = t; i < NBUCK; i += 256) cnt[i] = 0;
  __syncthreads();
  int s[16], g[16];
#pragma unroll
  for (int i = 0; i < 16; ++i) {
    const int e = ebase + i * 256 + t;
    const bool v = e < n;
    s[i] = v ? src[e] : 0;
    g[i] = v ? tgt[e] : -1;
    if (v) {
      atomicAdd(&cnt[g[i] >> 8], 1);
      atomicAdd(&deg[g[i]], 1);          // global per-node degree (L2-resident 400KB)
    }
  }
  __syncthreads();
  for (int i = t; i < NBUCK; i += 256) {       // reserve global space, reset local cursor
    const int c = cnt[i];
    base[i] = c ? atomicAdd(&gcur[i], c) : 0;
    cnt[i] = 0;
  }
  __syncthreads();
#pragma unroll
  for (int i = 0; i < 16; ++i) {
    if (g[i] >= 0) {
      const int bkt = g[i] >> 8;
      const int pos = base[bkt] + atomicAdd(&cnt[bkt], 1);
      if (pos < capb) gbin[bkt * capb + pos] = (s[i] << 8) | (g[i] & 255);
    }
  }
}

// ---------------- fused: bucket scans (2 blocks)  ||  dinv = rsqrt(deg+1) ----------------
__global__ __launch_bounds__(512) void k_scand(
    const int* __restrict__ gcur_s, int* __restrict__ bscan_s,
    const int* __restrict__ gcur_k, int* __restrict__ bscan_k,
    const int* __restrict__ deg_s, float* __restrict__ dinv_s,
    const int* __restrict__ deg_k, float* __restrict__ dinv_k) {
  __shared__ int sd[512];
  const int t = threadIdx.x;
  if (blockIdx.x >= 2) {                       // ---- dinv path ----
    const int i = (blockIdx.x - 2) * 512 + t;
    if (i < NN) dinv_s[i] = rsqrtf((float)(deg_s[i] + 1));
    else if (i < 2 * NN) dinv_k[i - NN] = rsqrtf((float)(deg_k[i - NN] + 1));
    return;
  }
  const int* gcur = blockIdx.x ? gcur_k : gcur_s;
  int* bscan      = blockIdx.x ? bscan_k : bscan_s;
  const int v = (t < NBUCK) ? gcur[t] : 0;
  sd[t] = v;
  __syncthreads();
  for (int off = 1; off < 512; off <<= 1) {
    const int x = (t >= off) ? sd[t - off] : 0;
    __syncthreads(); sd[t] += x; __syncthreads();
  }
  if (t < NBUCK) bscan[t] = sd[t] - v;   // exclusive
}

// ---------------- fused: per-bucket CSR (1-pass, w fused)  ||  GEMM1 ----------------
// csr: cnt comes from the global deg histogram (bucket b holds exactly nodes 256b..256b+255),
// so the counting pass over gbin is gone; the scatter writes {src, dinv[src]} directly.
union SMemCG {
  struct { int cnt[256]; int base[256]; } c;
  struct { float A[2][2048]; unsigned short B[2][4096]; } g;
};

__global__ __launch_bounds__(256) void k_csrg1(
    // csr args
    const int* __restrict__ gcur_s, const int* __restrict__ gbin_s, const int* __restrict__ bscan_s,
    int* __restrict__ rp_s, int2* __restrict__ colw_s,
    const int* __restrict__ deg_s, const float* __restrict__ dinv_s,
    const int* __restrict__ gcur_k, const int* __restrict__ gbin_k, const int* __restrict__ bscan_k,
    int* __restrict__ rp_k, int2* __restrict__ colw_k,
    const int* __restrict__ deg_k, const float* __restrict__ dinv_k,
    // gemm1 args
    const float* __restrict__ x, const unsigned short* __restrict__ W1T,
    const float* __restrict__ zbuf, unsigned short* __restrict__ H1b) {
  __shared__ SMemCG sm;
  const int t = threadIdx.x;

  if (blockIdx.x < 2 * NBUCK) {
    // ================= csr path (1-pass) =================
    int* cnt  = sm.c.cnt;
    int* base = sm.c.base;
    const int b0 = blockIdx.x;
    const bool knn = (b0 >= NBUCK);
    const int b = knn ? b0 - NBUCK : b0;
    const int* gcur  = knn ? gcur_k  : gcur_s;
    const int* gbin  = knn ? gbin_k  : gbin_s;
    const int* bscan = knn ? bscan_k : bscan_s;
    const int* deg   = knn ? deg_k   : deg_s;
    const float* dv  = knn ? dinv_k  : dinv_s;
    int* rp     = knn ? rp_k   : rp_s;
    int2* colw  = knn ? colw_k : colw_s;
    const int capb = knn ? CAPB_K : CAPB_S;
    int nB = gcur[b]; if (nB > capb) nB = capb;
    const int gb0 = b * capb;
    const int gbase = bscan[b];
    const int tg = b * 256 + t;

    const int myc = (tg < NN) ? deg[tg] : 0;   // == this bucket's per-node edge count
    base[t] = myc;
    __syncthreads();
    for (int off = 1; off < 256; off <<= 1) {  // inclusive Hillis-Steele
      const int x2 = (t >= off) ? base[t - off] : 0;
      __syncthreads(); base[t] += x2; __syncthreads();
    }
    const int excl = base[t] - myc;
    if (tg < NN) rp[tg] = gbase + excl;
    if (tg == NN) rp[NN] = gbase + excl;       // only in last bucket (t=160)
    __syncthreads();
    base[t] = excl; cnt[t] = 0;
    __syncthreads();
    for (int i = t; i < nB; i += 256) {
      const int e = gbin[gb0 + i];
      const int tl = e & 255;
      const int srcn = e >> 8;
      const int pos = atomicAdd(&cnt[tl], 1);
      colw[gbase + base[tl] + pos] = make_int2(srcn, __float_as_int(dv[srcn]));
    }
    return;
  }

  // ================= gemm1 path (BM=64, dbuf, vmcnt(4), swizzled staging) ====
  const int wv = t >> 6, lane = t & 63;
  const int qd = lane >> 4, mr = lane & 15;
  const int m0 = (blockIdx.x - 2 * NBUCK) * 64;

  float4v acc[8];
  const float4v zf4 = {0.f, 0.f, 0.f, 0.f};
#pragma unroll
  for (int b = 0; b < 8; ++b) acc[b] = zf4;

  auto stage = [&](int kk, int pb) {
    const int k0 = kk * 32;
#pragma unroll
    for (int i = 0; i < 2; ++i) {
      const int q = (wv * 2 + i) * 64 + lane;      // A sidx
      const int m = q >> 3;
      const int kg = (q & 7) ^ (m & 7);            // inverse swizzle on global src
      const int gm = m0 + m, kb = k0 + kg * 4;     // 500 % 4 == 0 -> never straddles
      const float* gp = (gm < NN && kb < FIN) ? (x + (size_t)gm * FIN + kb) : zbuf;
      gl_lds16(gp, &sm.g.A[pb][q * 4]);
    }
#pragma unroll
    for (int i = 0; i < 2; ++i) {
      const int q = (wv * 2 + i) * 64 + lane;      // B sidx
      const int n = q >> 2;
      const int kg = (q & 3) ^ ((q >> 3) & 3);     // (n>>1)&3 = (q>>3)&3
      gl_lds16(W1T + n * KP1 + k0 + kg * 8, &sm.g.B[pb][q * 8]);
    }
  };

  stage(0, 0);                                   // prologue: tile 0 in flight
  for (int kk = 0; kk < 16; ++kk) {
    const int cur = kk & 1;
    if (kk + 1 < 16) {
      stage(kk + 1, cur ^ 1);                    // issue next tile (8 outstanding)
      asm volatile("s_waitcnt vmcnt(4)" ::: "memory");   // oldest 4 (tile kk) done
    } else {
      asm volatile("s_waitcnt vmcnt(0)" ::: "memory");
    }
    __builtin_amdgcn_s_barrier();                // all waves' tile-kk writes complete

    short8 af;                                   // A frag: A[m][k=qd*8+j]
    {
      const int m = wv * 16 + mr;
      const int s0 = m * 8 + ((2 * qd) ^ (m & 7));
      const int s1 = m * 8 + ((2 * qd + 1) ^ (m & 7));
      const float4v a0 = *(const float4v*)&sm.g.A[cur][s0 * 4];
      const float4v a1 = *(const float4v*)&sm.g.A[cur][s1 * 4];
      af[0] = (short)f2bf(a0[0]); af[1] = (short)f2bf(a0[1]);
      af[2] = (short)f2bf(a0[2]); af[3] = (short)f2bf(a0[3]);
      af[4] = (short)f2bf(a1[0]); af[5] = (short)f2bf(a1[1]);
      af[6] = (short)f2bf(a1[2]); af[7] = (short)f2bf(a1[3]);
    }
#pragma unroll
    for (int ct = 0; ct < 8; ++ct) {             // B frag: B[k=qd*8+j][n=ct*16+mr]
      const int n = ct * 16 + mr;
      const int sb = n * 4 + (qd ^ ((n >> 1) & 3));
      const short8 bf = *(const short8*)&sm.g.B[cur][sb * 8];
      acc[ct] = __builtin_amdgcn_mfma_f32_16x16x32_bf16(af, bf, acc[ct], 0, 0, 0);
    }
    __builtin_amdgcn_s_barrier();                // reads done before next stage overwrites
  }

  // C/D layout: col = lane&15, row = (lane>>4)*4 + j
  const int rb = m0 + wv * 16 + qd * 4;
#pragma unroll
  for (int ct = 0; ct < 8; ++ct) {
    const int col = ct * 16 + mr;
#pragma unroll
    for (int j = 0; j < 4; ++j) {
      const int r = rb + j;
      if (r < NN) H1b[(size_t)r * HID + col] = f2bf(acc[ct][j]);
    }
  }
}

// ---------------- GEMM2 v3: PQ = bf16(R1b @ Wpq)  [NN x 80] ----------------
__global__ __launch_bounds__(256) void k_gemm2(const unsigned short* __restrict__ R1b,
    const unsigned short* __restrict__ WpqT, const unsigned short* __restrict__ zbuf,
    unsigned short* __restrict__ PQ) {
  __shared__ unsigned short Als[2][256 * 8];   // 64 m x 4 kg elems
  __shared__ unsigned short Bls[2][512 * 8];   // 128 n x 4 kg elems (rows 80..127 pad)
  const int t = threadIdx.x;
  const int wv = t >> 6, lane = t & 63;
  const int qd = lane >> 4, mr = lane & 15;
  const int m0 = blockIdx.x * 64;

  float4v acc[5];
  const float4v zf4 = {0.f, 0.f, 0.f, 0.f};
#pragma unroll
  for (int b = 0; b < 5; ++b) acc[b] = zf4;

  auto stage = [&](int kk, int pb) {
    const int k0 = kk * 32;
    {
      const int q = wv * 64 + lane;              // A sidx (256 total)
      const int m = q >> 2;
      const int kg = (q & 3) ^ ((q >> 3) & 3);
      const int gm = m0 + m;
      const unsigned short* gp = (gm < NN) ? (R1b + (size_t)gm * K2 + k0 + kg * 8) : zbuf;
      gl_lds16(gp, &Als[pb][q * 8]);
    }
#pragma unroll
    for (int i = 0; i < 2; ++i) {
      const int q = (wv * 2 + i) * 64 + lane;    // B sidx (512 total)
      const int n = q >> 2;
      const int kg = (q & 3) ^ ((q >> 3) & 3);
      gl_lds16(WpqT + n * K2 + k0 + kg * 8, &Bls[pb][q * 8]);
    }
  };

  stage(0, 0);
  for (int kk = 0; kk < 8; ++kk) {
    const int cur = kk & 1;
    if (kk + 1 < 8) {
      stage(kk + 1, cur ^ 1);
      asm volatile("s_waitcnt vmcnt(3)" ::: "memory");
    } else {
      asm volatile("s_waitcnt vmcnt(0)" ::: "memory");
    }
    __builtin_amdgcn_s_barrier();

    short8 af;
    {
      const int m = wv * 16 + mr;
      const int sa = m * 4 + (qd ^ ((m >> 1) & 3));
      af = *(const short8*)&Als[cur][sa * 8];
    }
#pragma unroll
    for (int ct = 0; ct < 5; ++ct) {
      const int n = ct * 16 + mr;
      const int sb = n * 4 + (qd ^ ((n >> 1) & 3));
      const short8 bf = *(const short8*)&Bls[cur][sb * 8];
      acc[ct] = __builtin_amdgcn_mfma_f32_16x16x32_bf16(af, bf, acc[ct], 0, 0, 0);
    }
    __builtin_amdgcn_s_barrier();
  }

  const int rb = m0 + wv * 16 + qd * 4;
#pragma unroll
  for (int ct = 0; ct < 5; ++ct) {
    const int col = ct * 16 + mr;
#pragma unroll
    for (int j = 0; j < 4; ++j) {
      const int r = rb + j;
      if (r < NN) PQ[(size_t)r * NPQ + col] = f2bf(acc[ct][j]);
    }
  }
}

// ---------------- gather helpers v4: scalar index batches + pipelined gathers ----------------
__device__ __forceinline__ void ld8(const int2* __restrict__ cw, int base, int e1, bool full,
                                    int2* __restrict__ q) {
  if (full) {
#pragma unroll
    for (int j = 0; j < 8; ++j) q[j] = cw[base + j];
  } else {
    const int e1c = e1 - 1;
#pragma unroll
    for (int j = 0; j < 8; ++j) {
      const int ee = base + j;
      int2 t = cw[(ee < e1) ? ee : e1c];
      t.y = (ee < e1) ? t.y : 0;
      q[j] = t;
    }
  }
}
__device__ __forceinline__ void g8(const int2* __restrict__ q,
    const unsigned* __restrict__ H32, int lane, unsigned* __restrict__ d) {
#pragma unroll
  for (int j = 0; j < 8; ++j) d[j] = H32[(size_t)q[j].x * 64 + lane];
}
__device__ __forceinline__ void f8(const int2* __restrict__ q, const unsigned* __restrict__ d,
                                   float& ax, float& ay) {
#pragma unroll
  for (int j = 0; j < 8; ++j) {
    const float w = __int_as_float(q[j].y);
    ax += w * __uint_as_float(d[j] << 16);
    ay += w * __uint_as_float(d[j] & 0xffff0000u);
  }
}

// ---------------- layer-1 aggregation: one wave per node, BOTH graphs ----------------
__global__ __launch_bounds__(256) void k_agg1(
    const int* __restrict__ rp_s, const int2* __restrict__ colw_s, const float* __restrict__ dinv_s,
    const int* __restrict__ rp_k, const int2* __restrict__ colw_k, const float* __restrict__ dinv_k,
    const unsigned short* __restrict__ H, const float* __restrict__ bias,
    unsigned short* __restrict__ out) {
  const int wv = threadIdx.x >> 6, lane = threadIdx.x & 63;
  const int c = blockIdx.x * 4 + wv;
  if (c >= NN) return;
  const unsigned* H32 = (const unsigned*)H;
  const int e0s = __builtin_amdgcn_readfirstlane(rp_s[c]);
  const int e1s = __builtin_amdgcn_readfirstlane(rp_s[c + 1]);
  const int e0k = __builtin_amdgcn_readfirstlane(rp_k[c]);
  const int e1k = __builtin_amdgcn_readfirstlane(rp_k[c + 1]);
  const int nbS = (e1s - e0s + 7) >> 3;   // may be 0
  const int nbK = (e1k - e0k + 7) >> 3;

  int2 q0[8], q1[8], qk[8];
  unsigned d0[8], d1[8], dk[8];
  // issue phase: self row + structural batches 0,1 + knn batch 0 all in flight
  const unsigned pc = H32[(size_t)c * 64 + lane];
  if (nbS > 0) { ld8(colw_s, e0s, e1s, e0s + 8 <= e1s, q0); g8(q0, H32, lane, d0); }
  if (nbS > 1) { ld8(colw_s, e0s + 8, e1s, e0s + 16 <= e1s, q1); g8(q1, H32, lane, d1); }
  if (nbK > 0) { ld8(colw_k, e0k, e1k, e0k + 8 <= e1k, qk); g8(qk, H32, lane, dk); }

  const float dcs = dinv_s[c], dck = dinv_k[c];
  const float slo = __uint_as_float(pc << 16);
  const float shi = __uint_as_float(pc & 0xffff0000u);
  float ax = dcs * slo, ay = dcs * shi;   // structural self
  float bx = dck * slo, by = dck * shi;   // knn self

  // structural: pairwise ping-pong, always ~16 gathers outstanding
  int b = 0;
  while (b + 2 < nbS) {
    f8(q0, d0, ax, ay);                   // consume batch b
    {
      const int bs = e0s + (b + 2) * 8;   // issue batch b+2
      ld8(colw_s, bs, e1s, bs + 8 <= e1s, q0);
      g8(q0, H32, lane, d0);
    }
    f8(q1, d1, ax, ay);                   // consume batch b+1
    if (b + 3 < nbS) {
      const int bs = e0s + (b + 3) * 8;   // issue batch b+3
      ld8(colw_s, bs, e1s, bs + 8 <= e1s, q1);
      g8(q1, H32, lane, d1);
    }
    b += 2;
  }
  if (b < nbS) f8(q0, d0, ax, ay);
  if (b + 1 < nbS) f8(q1, d1, ax, ay);

  // knn: batch 0 already in flight since the top; extra batches are rare (deg>8)
  if (nbK > 0) f8(qk, dk, bx, by);
  for (int bk = 1; bk < nbK; ++bk) {
    const int bs = e0k + bk * 8;
    ld8(colw_k, bs, e1k, bs + 8 <= e1k, qk);
    g8(qk, H32, lane, dk);
    f8(qk, dk, bx, by);
  }

  const float2 bb = ((const float2*)bias)[lane];
  const float o0 = fmaxf(dcs * ax + bb.x, 0.f);
  const float o1 = fmaxf(dcs * ay + bb.y, 0.f);
  const float o2 = fmaxf(dck * bx + bb.x, 0.f);
  const float o3 = fmaxf(dck * by + bb.y, 0.f);
  unsigned* orow = (unsigned*)(out + (size_t)c * K2);
  orow[lane]      = (unsigned)f2bf(o0) | ((unsigned)f2bf(o1) << 16);
  orow[64 + lane] = (unsigned)f2bf(o2) | ((unsigned)f2bf(o3) << 16);
}

// ---------------- tail v2: logits = agg_s(P) + agg_k(Q) + cb; log_softmax ----------------
__device__ __forceinline__ void ld12(const int2* __restrict__ cw, int base, int e1, bool full,
                                     int2* __restrict__ q) {
  if (full) {
#pragma unroll
    for (int j = 0; j < 12; ++j) q[j] = cw[base + j];
  } else {
    const int e1c = e1 - 1;
#pragma unroll
    for (int j = 0; j < 12; ++j) {
      const int ee = base + j;
      int2 t = cw[(ee < e1) ? ee : e1c];
      t.y = (ee < e1) ? t.y : 0;
      q[j] = t;
    }
  }
}
__device__ __forceinline__ void gt4(const int2* __restrict__ q, const unsigned* __restrict__ PQ32,
                                    int g, int l, int off, float* __restrict__ w,
                                    unsigned* __restrict__ d) {
#pragma unroll
  for (int t = 0; t < 4; ++t) {
    const int2 qa = q[3 * t], qb = q[3 * t + 1], qc = q[3 * t + 2];
    const int xs = (g == 0) ? qa.x : ((g == 1) ? qb.x : qc.x);
    const int wi = (g == 0) ? qa.y : ((g == 1) ? qb.y : qc.y);
    w[t] = __int_as_float(wi);
    d[t] = PQ32[(size_t)xs * 40 + off + l];
  }
}
__device__ __forceinline__ void ct4(const float* __restrict__ w, const unsigned* __restrict__ d,
                                    float& sx, float& sy) {
#pragma unroll
  for (int t = 0; t < 4; ++t) {
    sx += w[t] * __uint_as_float(d[t] << 16);
    sy += w[t] * __uint_as_float(d[t] & 0xffff0000u);
  }
}

__global__ __launch_bounds__(256) void k_aggf(
    const int* __restrict__ rp_s, const int2* __restrict__ colw_s, const float* __restrict__ dinv_s,
    const int* __restrict__ rp_k, const int2* __restrict__ colw_k, const float* __restrict__ dinv_k,
    const unsigned short* __restrict__ PQ, const float* __restrict__ cb,
    float* __restrict__ out) {
  const int wv = threadIdx.x >> 6, lane = threadIdx.x & 63;
  const int c = blockIdx.x * 4 + wv;
  if (c >= NN) return;
  const unsigned* PQ32 = (const unsigned*)PQ;
  const int g = (lane < 60) ? (lane / 20) : 2;   // lanes 60-63 ride with g=2 (results unused)
  const int l = lane - 20 * g;                   // 0..19 active; 20..23 for lanes 60-63 (safe)

  const int e0s = __builtin_amdgcn_readfirstlane(rp_s[c]);
  const int e1s = __builtin_amdgcn_readfirstlane(rp_s[c + 1]);
  const int e0k = __builtin_amdgcn_readfirstlane(rp_k[c]);
  const int e1k = __builtin_amdgcn_readfirstlane(rp_k[c + 1]);
  const int nbS = (e1s - e0s + 11) / 12;
  const int nbK = (e1k - e0k + 11) / 12;

  // self rows issued up-front (consumed at the end)
  unsigned dP = 0, dQ = 0;
  if (lane < 20) {
    dP = PQ32[(size_t)c * 40 + lane];
    dQ = PQ32[(size_t)c * 40 + 20 + lane];
  }

  int2 q0[12], q1[12], qk[12];
  float w0[4], w1[4], wk[4];
  unsigned d0[4], d1[4], dk[4];
  if (nbS > 0) { ld12(colw_s, e0s, e1s, e0s + 12 <= e1s, q0); gt4(q0, PQ32, g, l, 0, w0, d0); }
  if (nbS > 1) { ld12(colw_s, e0s + 12, e1s, e0s + 24 <= e1s, q1); gt4(q1, PQ32, g, l, 0, w1, d1); }
  if (nbK > 0) { ld12(colw_k, e0k, e1k, e0k + 12 <= e1k, qk); gt4(qk, PQ32, g, l, 20, wk, dk); }

  float sx = 0.f, sy = 0.f, kx = 0.f, ky = 0.f;
  int b = 0;
  while (b + 2 < nbS) {
    ct4(w0, d0, sx, sy);
    {
      const int bs = e0s + (b + 2) * 12;
      ld12(colw_s, bs, e1s, bs + 12 <= e1s, q0);
      gt4(q0, PQ32, g, l, 0, w0, d0);
    }
    ct4(w1, d1, sx, sy);
    if (b + 3 < nbS) {
      const int bs = e0s + (b + 3) * 12;
      ld12(colw_s, bs, e1s, bs + 12 <= e1s, q1);
      gt4(q1, PQ32, g, l, 0, w1, d1);
    }
    b += 2;
  }
  if (b < nbS) ct4(w0, d0, sx, sy);
  if (b + 1 < nbS) ct4(w1, d1, sx, sy);

  if (nbK > 0) ct4(wk, dk, kx, ky);
  for (int bk = 1; bk < nbK; ++bk) {
    const int bs = e0k + bk * 12;
    ld12(colw_k, bs, e1k, bs + 12 <= e1k, qk);
    gt4(qk, PQ32, g, l, 20, wk, dk);
    ct4(wk, dk, kx, ky);
  }

  // combine 3 group partials into lanes 0-19
  sx += __shfl(sx, lane + 20) + __shfl(sx, lane + 40);
  sy += __shfl(sy, lane + 20) + __shfl(sy, lane + 40);
  kx += __shfl(kx, lane + 20) + __shfl(kx, lane + 40);
  ky += __shfl(ky, lane + 20) + __shfl(ky, lane + 40);

  float lo = 0.f, hi = 0.f;
  if (lane < 20) {
    const float dcs = dinv_s[c], dck = dinv_k[c];
    const float2 cbb = ((const float2*)cb)[lane];
    lo = dcs * (sx + dcs * __uint_as_float(dP << 16))
       + dck * (kx + dck * __uint_as_float(dQ << 16)) + cbb.x;
    hi = dcs * (sy + dcs * __uint_as_float(dP & 0xffff0000u))
       + dck * (ky + dck * __uint_as_float(dQ & 0xffff0000u)) + cbb.y;
  }
  // log_softmax over 40 (lanes 0-19 hold pairs)
  float m = (lane < 20) ? fmaxf(lo, hi) : -3.4e38f;
#pragma unroll
  for (int off = 1; off < 64; off <<= 1) m = fmaxf(m, __shfl_xor(m, off));
  float s = (lane < 20) ? (expf(lo - m) + expf(hi - m)) : 0.f;
#pragma unroll
  for (int off = 1; off < 64; off <<= 1) s += __shfl_xor(s, off);
  const float lse = m + logf(s);
  if (lane < 20) {
    float2 o; o.x = lo - lse; o.y = hi - lse;
    ((float2*)(out + (size_t)c * CO))[lane] = o;
  }
}

extern "C" void kernel_launch(void* const* d_in, const int* in_sizes, int n_in,
                              void* d_out, int out_size, void* d_ws, size_t ws_size,
                              hipStream_t stream) {
  const float* x  = (const float*)d_in[0];
  const int* ei   = (const int*)d_in[1];   // [2][E]: row0 = src, row1 = tgt
  const int* eik  = (const int*)d_in[2];
  const float* W1 = (const float*)d_in[3];
  const float* b1 = (const float*)d_in[4];
  const float* W2 = (const float*)d_in[5];
  const float* b2 = (const float*)d_in[6];
  const float* Wl = (const float*)d_in[7];
  const float* bl = (const float*)d_in[8];
  float* out = (float*)d_out;
  const int E  = in_sizes[1] / 2;
  const int EK = in_sizes[2] / 2;

  // workspace layout (~125 MB), 256B-aligned slots
  char* p = (char*)d_ws;
  size_t off = 0;
  auto alloc = [&](size_t bytes) -> void* {
    void* r = (void*)(p + off);
    off += (bytes + 255) & ~(size_t)255;
    return r;
  };
  int* gcur_s = (int*)alloc((size_t)NBUCK * 4);
  int* gcur_k = (int*)alloc((size_t)NBUCK * 4);
  int* deg_s  = (int*)alloc((size_t)NN * 4);    // zeroed
  int* deg_k  = (int*)alloc((size_t)NN * 4);    // zeroed
  void* zbuf = alloc(256);                 // zero redirect target for OOB tiles
  const size_t zero_span = off;            // memset covers gcur_*, deg_*, zbuf
  int* bscan_s = (int*)alloc((size_t)NBUCK * 4);
  int* bscan_k = (int*)alloc((size_t)NBUCK * 4);
  float* dinv_s = (float*)alloc((size_t)NN * 4);
  float* dinv_k = (float*)alloc((size_t)NN * 4);
  int* rp_s = (int*)alloc((size_t)(NN + 1) * 4);
  int* rp_k = (int*)alloc((size_t)(NN + 1) * 4);
  unsigned short* W1T = (unsigned short*)alloc((size_t)HID * KP1 * 2);
  unsigned short* WpqT = (unsigned short*)alloc((size_t)NPQP * K2 * 2);  // rows 80..127 pad
  float* cbv = (float*)alloc((size_t)CO * 4);
  int* gbin_s = (int*)alloc((size_t)NBUCK * CAPB_S * 4);    // 14.4 MB
  int* gbin_k = (int*)alloc((size_t)NBUCK * CAPB_K * 4);    // 2.4 MB
  int2* colw_s = (int2*)alloc((size_t)E * 8);               // 25.6 MB
  int2* colw_k = (int2*)alloc((size_t)EK * 8);              // 4 MB
  unsigned short* H1b = (unsigned short*)alloc((size_t)NN * HID * 2);   // 25.6 MB
  unsigned short* R1b = (unsigned short*)alloc((size_t)NN * K2 * 2);    // 51.2 MB
  unsigned short* PQ = H1b;   // alias: H1b dead after agg1; PQ = [NN x 80] bf16 (16 MB)

  hipMemsetAsync(d_ws, 0, zero_span, stream);

  // fused: bin (+deg histogram) || w1t || wpq  (all depend only on inputs)
  const int nb1S = (E + 4095) / 4096;
  const int nb1K = (EK + 4095) / 4096;
  const int nbBin = nb1S + nb1K;
  k_binw<<<nbBin + 256 + NPQ, 256, 0, stream>>>(
      ei, E, nb1S, gcur_s, gbin_s, eik, EK, nbBin, gcur_k, gbin_k,
      deg_s, deg_k, W1, W1T, W2, Wl, b2, bl, WpqT, cbv);

  // fused: bucket scans || dinv = rsqrt(deg+1)
  const int nbD = (2 * NN + 511) / 512;
  k_scand<<<2 + nbD, 512, 0, stream>>>(gcur_s, bscan_s, gcur_k, bscan_k,
                                       deg_s, dinv_s, deg_k, dinv_k);

  // fused: csr (1-pass, w fused; needs bin+scand) || gemm1 (needs x, W1T)
  const int nbG1 = (NN + 63) / 64;
  k_csrg1<<<2 * NBUCK + nbG1, 256, 0, stream>>>(
      gcur_s, gbin_s, bscan_s, rp_s, colw_s, deg_s, dinv_s,
      gcur_k, gbin_k, bscan_k, rp_k, colw_k, deg_k, dinv_k,
      x, W1T, (const float*)zbuf, H1b);

  const int nbAgg = (NN + 3) / 4;
  k_agg1<<<nbAgg, 256, 0, stream>>>(rp_s, colw_s, dinv_s, rp_k, colw_k, dinv_k, H1b, b1, R1b);

  // folded tail: PQ GEMM (BM=64 dbuf, swizzled staging) + fused aggregation/log_softmax
  k_gemm2<<<(NN + 63) / 64, 256, 0, stream>>>(R1b, WpqT, (const unsigned short*)zbuf, PQ);
  k_aggf<<<nbAgg, 256, 0, stream>>>(rp_s, colw_s, dinv_s, rp_k, colw_k, dinv_k, PQ, cbv, out);
}